// Round 10
// baseline (674.111 us; speedup 1.0000x reference)
//
#include <hip/hip_runtime.h>
#include <hip/hip_bf16.h>
#include <cstdint>
#include <cstddef>

#define N_NODES 100000
#define N_EDGES 1600000
#define F_IN    256
#define HID     128
#define NB       ((N_NODES + 255) >> 8)                        // 391 dst-buckets
#define F3_CHUNK 7168
#define N_CHUNKS ((N_EDGES + F3_CHUNK - 1) / F3_CHUNK)         // 224
#define ITEMS_PER_SLICE (N_NODES / 32)                         // 3125
#define QSTRIDE 16                                             // 64B-padded queue counters
#define GATHER_BLOCKS 2048

typedef __attribute__((ext_vector_type(8))) short  bf16x8;
typedef __attribute__((ext_vector_type(4))) float  f32x4;

static __device__ inline float bf2f(unsigned short u) {
    return __uint_as_float(((unsigned int)u) << 16);
}
static __device__ inline unsigned short f2bf(float f) {
    union { __hip_bfloat16 h; unsigned short u; } c;
    c.h = __float2bfloat16(f);
    return c.u;
}
static __device__ inline float lof(unsigned int w) { return __uint_as_float(w << 16); }
static __device__ inline float hif(unsigned int w) { return __uint_as_float(w & 0xffff0000u); }

// ---------------- utility ----------------

__global__ __launch_bounds__(256) void zero_f_kernel(float* __restrict__ p, int n) {
    int i = blockIdx.x * 256 + threadIdx.x;
    if (i < n) p[i] = 0.f;
}

// ---------------- bucketed CSR build ----------------

__global__ __launch_bounds__(256) void count_kernel(const int* __restrict__ dst,
                                                    int* __restrict__ ccnt, int nE) {
    __shared__ int c[NB];
    for (int i = threadIdx.x; i < NB; i += 256) c[i] = 0;
    __syncthreads();
    int base = blockIdx.x * F3_CHUNK;
    int m = min(F3_CHUNK, nE - base);
    for (int t = threadIdx.x; t < m; t += 256)
        atomicAdd(&c[dst[base + t] >> 8], 1);
    __syncthreads();
    for (int i = threadIdx.x; i < NB; i += 256)
        ccnt[i * N_CHUNKS + blockIdx.x] = c[i];
}

__global__ __launch_bounds__(256) void scanA_kernel(int* __restrict__ ccnt,
                                                    int* __restrict__ btot) {
    __shared__ int s[256];
    const int b = blockIdx.x;
    const int t = threadIdx.x;
    int v = (t < N_CHUNKS) ? ccnt[b * N_CHUNKS + t] : 0;
    s[t] = v;
    __syncthreads();
    for (int off = 1; off < 256; off <<= 1) {
        int add = (t >= off) ? s[t - off] : 0;
        __syncthreads();
        s[t] += add;
        __syncthreads();
    }
    if (t < N_CHUNKS) ccnt[b * N_CHUNKS + t] = s[t] - v;
    if (t == 255) btot[b] = s[255];
}

// scanB also zeroes the 3x8 padded gather work-queues

__global__ __launch_bounds__(512) void scanB_kernel(const int* __restrict__ btot,
                                                    int* __restrict__ bbase,
                                                    int* __restrict__ qcAll) {
    __shared__ int s[512];
    int t = threadIdx.x;
    if (t < 3 * 8 * QSTRIDE) qcAll[t] = 0;
    int v = (t < NB) ? btot[t] : 0;
    s[t] = v;
    __syncthreads();
    for (int off = 1; off < 512; off <<= 1) {
        int add = (t >= off) ? s[t - off] : 0;
        __syncthreads();
        s[t] += add;
        __syncthreads();
    }
    if (t < NB) bbase[t] = s[t] - v;
    if (t == 0) bbase[NB] = N_EDGES;
}

__global__ __launch_bounds__(256) void stage_kernel(const int* __restrict__ src,
                                                    const int* __restrict__ dst,
                                                    const int* __restrict__ ccnt,
                                                    const int* __restrict__ bbase,
                                                    unsigned int* __restrict__ stg, int nE) {
    __shared__ int cnt[NB];
    __shared__ int bas[NB];
    const int chunk = blockIdx.x;
    for (int i = threadIdx.x; i < NB; i += 256) {
        cnt[i] = 0;
        bas[i] = bbase[i] + ccnt[i * N_CHUNKS + chunk];
    }
    __syncthreads();
    int base = chunk * F3_CHUNK;
    int m = min(F3_CHUNK, nE - base);
    for (int t = threadIdx.x; t < m; t += 256) {
        int d = dst[base + t];
        int s = src[base + t];
        int bkt = d >> 8;
        int k = atomicAdd(&cnt[bkt], 1);
        stg[bas[bkt] + k] = ((unsigned int)s << 8) | (unsigned int)(d & 255);
    }
}

__global__ __launch_bounds__(256) void bucket_finalize_kernel(
        const unsigned int* __restrict__ stg,
        const int* __restrict__ bbase,
        float* __restrict__ dinv,
        int* __restrict__ row_ptr,
        int* __restrict__ csr_src, int n) {
    __shared__ int c[256];
    __shared__ int s[256];
    __shared__ int lofs[256];
    const int b = blockIdx.x;
    const int t = threadIdx.x;
    const int beg = bbase[b], end = bbase[b + 1];

    c[t] = 0;
    __syncthreads();
    for (int i = beg + t; i < end; i += 256)
        atomicAdd(&c[stg[i] & 255u], 1);
    __syncthreads();

    const int node = b * 256 + t;
    const int myDeg = c[t];
    if (node < n) dinv[node] = rsqrtf((float)myDeg + 1.0f);   // +1 self-loop

    s[t] = myDeg;
    __syncthreads();
    for (int off = 1; off < 256; off <<= 1) {
        int add = (t >= off) ? s[t - off] : 0;
        __syncthreads();
        s[t] += add;
        __syncthreads();
    }
    const int excl = s[t] - myDeg;
    lofs[t] = excl;
    if (node <= n) row_ptr[node] = beg + excl;

    __syncthreads();
    c[t] = 0;
    __syncthreads();
    for (int i = beg + t; i < end; i += 256) {
        unsigned int p = stg[i];
        int dl = (int)(p & 255u);
        int k = atomicAdd(&c[dl], 1);
        csr_src[beg + lofs[dl] + k] = (int)(p >> 8);
    }
}

// ---------------- W -> fragment blobs ----------------

static __device__ inline void blob_fill(const float* __restrict__ W,
                                        unsigned short* __restrict__ blob, int tid) {
    int lane = tid & 63;
    int c    = (tid >> 6) & 7;
    int s    = tid >> 9;
    int col  = c * 16 + (lane & 15);
    int kb   = s * 32 + (lane >> 4) * 8;
    bf16x8 o;
#pragma unroll
    for (int j = 0; j < 8; ++j)
        o[j] = (short)f2bf(W[(size_t)(kb + j) * HID + col]);
    *reinterpret_cast<bf16x8*>(blob + (size_t)tid * 8) = o;
}

__global__ __launch_bounds__(256) void prep_blob_all_kernel(const float* __restrict__ W1,
                                                            const float* __restrict__ W2,
                                                            const float* __restrict__ W3,
                                                            unsigned short* __restrict__ blob1,
                                                            unsigned short* __restrict__ blob2,
                                                            unsigned short* __restrict__ blob3) {
    int blk = blockIdx.x;
    if (blk < 16) {
        blob_fill(W1, blob1, blk * 256 + threadIdx.x);
    } else if (blk < 24) {
        blob_fill(W2, blob2, (blk - 16) * 256 + threadIdx.x);
    } else {
        blob_fill(W3, blob3, (blk - 24) * 256 + threadIdx.x);
    }
}

// ---------------- MFMA GEMM, slice-major I/O -------------------------------
// Y layout: [8 slices][N][16 cols] bf16 (32 B rows per slice).
// slice of output col (c*16+col) is exactly c. A-read (bf16 input) maps
// k-chunk c0 = s*32+koff -> slice c0>>4, offset c0&15 (chunks never straddle).

template <int K, bool IN_BF16>
__global__ __launch_bounds__(256) void mfma_gemm_kernel(const void* __restrict__ Xv,
                                                        const unsigned short* __restrict__ blob,
                                                        unsigned short* __restrict__ Y, int n) {
    constexpr int KSTEPS = K / 32;
    const int lane = threadIdx.x & 63;
    const int wave = threadIdx.x >> 6;
    const int rowbase = blockIdx.x * 128 + wave * 32;

    const int r0 = min(rowbase +      (lane & 15), n - 1);
    const int r1 = min(rowbase + 16 + (lane & 15), n - 1);
    const int koff = (lane >> 4) * 8;

    f32x4 acc0[8], acc1[8];
#pragma unroll
    for (int c = 0; c < 8; ++c) { acc0[c] = (f32x4)0.f; acc1[c] = (f32x4)0.f; }

#pragma unroll
    for (int s = 0; s < KSTEPS; ++s) {
        bf16x8 bfr[8];
#pragma unroll
        for (int c = 0; c < 8; ++c)
            bfr[c] = *reinterpret_cast<const bf16x8*>(blob + ((size_t)((s * 8 + c) * 64 + lane)) * 8);

        bf16x8 a0, a1;
        if (IN_BF16) {
            const unsigned short* Xb = (const unsigned short*)Xv;
            const int c0 = s * 32 + koff;
            const int sl = c0 >> 4, o16 = c0 & 15;
            a0 = *reinterpret_cast<const bf16x8*>(Xb + ((size_t)(sl * N_NODES + r0)) * 16 + o16);
            a1 = *reinterpret_cast<const bf16x8*>(Xb + ((size_t)(sl * N_NODES + r1)) * 16 + o16);
        } else {
            const float* Xf = (const float*)Xv;
            const float4* p0 = reinterpret_cast<const float4*>(Xf + (size_t)r0 * K + s * 32 + koff);
            const float4* p1 = reinterpret_cast<const float4*>(Xf + (size_t)r1 * K + s * 32 + koff);
            float4 q0 = p0[0], q1 = p0[1], q2 = p1[0], q3 = p1[1];
            a0[0] = (short)f2bf(q0.x); a0[1] = (short)f2bf(q0.y);
            a0[2] = (short)f2bf(q0.z); a0[3] = (short)f2bf(q0.w);
            a0[4] = (short)f2bf(q1.x); a0[5] = (short)f2bf(q1.y);
            a0[6] = (short)f2bf(q1.z); a0[7] = (short)f2bf(q1.w);
            a1[0] = (short)f2bf(q2.x); a1[1] = (short)f2bf(q2.y);
            a1[2] = (short)f2bf(q2.z); a1[3] = (short)f2bf(q2.w);
            a1[4] = (short)f2bf(q3.x); a1[5] = (short)f2bf(q3.y);
            a1[6] = (short)f2bf(q3.z); a1[7] = (short)f2bf(q3.w);
        }

#pragma unroll
        for (int c = 0; c < 8; ++c) {
            acc0[c] = __builtin_amdgcn_mfma_f32_16x16x32_bf16(a0, bfr[c], acc0[c], 0, 0, 0);
            acc1[c] = __builtin_amdgcn_mfma_f32_16x16x32_bf16(a1, bfr[c], acc1[c], 0, 0, 0);
        }
    }

    const int col  = lane & 15;
    const int rsub = (lane >> 4) * 4;
#pragma unroll
    for (int c = 0; c < 8; ++c) {
#pragma unroll
        for (int r = 0; r < 4; ++r) {
            int row0 = rowbase + rsub + r;
            int row1 = rowbase + 16 + rsub + r;
            if (row0 < n) Y[((size_t)(c * N_NODES + row0)) * 16 + col] = f2bf(acc0[c][r]);
            if (row1 < n) Y[((size_t)(c * N_NODES + row1)) * 16 + col] = f2bf(acc1[c][r]);
        }
    }
}

// ---------------- XCD-affine sliced gather ---------------------------------
// xw/h slice-major [8][N][16]. Block reads its XCC_ID, pops 32-node items
// from its own slice's queue (steals when drained -> correctness mapping-free).
// Per wave: 8 nodes x 8 lanes (1 u32 = 2 cols per lane), no shuffles.

__global__ __launch_bounds__(256) void agg_gather_aff_kernel(
        const unsigned short* __restrict__ xw,
        const float* __restrict__ dinv,
        const int* __restrict__ row_ptr,
        const int* __restrict__ csr_src,
        const float* __restrict__ b,
        unsigned short* __restrict__ h,
        int* __restrict__ qc, int n) {
    __shared__ int s_item;
    int xcd;
    asm volatile("s_getreg_b32 %0, hwreg(20, 0, 32)" : "=s"(xcd));   // HW_REG_XCC_ID
    xcd &= 7;
    const int wave = threadIdx.x >> 6;
    const int lane = threadIdx.x & 63;
    const int grp  = lane >> 3;
    const int l8   = lane & 7;

    int attempt = 0;
    while (attempt < 8) {
        int q = (xcd + attempt) & 7;
        if (threadIdx.x == 0) s_item = atomicAdd(&qc[q * QSTRIDE], 1);
        __syncthreads();
        int item = s_item;
        __syncthreads();
        if (item >= ITEMS_PER_SLICE) { ++attempt; continue; }

        const unsigned int* xq = (const unsigned int*)xw + (size_t)q * n * 8;
        const int v = item * 32 + wave * 8 + grp;
        const int beg = row_ptr[v];
        const int end = row_ptr[v + 1];

        float a0 = 0.f, a1 = 0.f;
        int j = beg;
        for (; j + 2 <= end; j += 2) {
            int s0 = csr_src[j];
            int s1 = csr_src[j + 1];
            float d0 = dinv[s0], d1 = dinv[s1];
            unsigned int w0 = xq[(size_t)s0 * 8 + l8];
            unsigned int w1 = xq[(size_t)s1 * 8 + l8];
            a0 = fmaf(d0, lof(w0), a0); a1 = fmaf(d0, hif(w0), a1);
            a0 = fmaf(d1, lof(w1), a0); a1 = fmaf(d1, hif(w1), a1);
        }
        if (j < end) {
            int s0 = csr_src[j];
            float d0 = dinv[s0];
            unsigned int w0 = xq[(size_t)s0 * 8 + l8];
            a0 = fmaf(d0, lof(w0), a0); a1 = fmaf(d0, hif(w0), a1);
        }

        float dv = dinv[v];
        unsigned int wv = xq[(size_t)v * 8 + l8];
        float2 bb = *reinterpret_cast<const float2*>(b + q * 16 + l8 * 2);
        float s2v = dv * dv;
        float r0 = fmaxf(dv * a0 + s2v * lof(wv) + bb.x, 0.f);
        float r1 = fmaxf(dv * a1 + s2v * hif(wv) + bb.y, 0.f);
        unsigned int* hq = (unsigned int*)h + (size_t)q * n * 8;
        hq[(size_t)v * 8 + l8] = (unsigned int)f2bf(r0) | ((unsigned int)f2bf(r1) << 16);
    }
}

// ---------------- classifier + log_softmax (sliced h, post-relu) -----------

__global__ __launch_bounds__(256) void classifier_kernel(const unsigned short* __restrict__ h,
                                                         const float* __restrict__ Wc,
                                                         const float* __restrict__ bc,
                                                         float* __restrict__ out, int n) {
    __shared__ float wc0[HID], wc1[HID], bcs[2];
    if (threadIdx.x < HID) {
        wc0[threadIdx.x] = Wc[threadIdx.x * 2 + 0];
        wc1[threadIdx.x] = Wc[threadIdx.x * 2 + 1];
    }
    if (threadIdx.x < 2) bcs[threadIdx.x] = bc[threadIdx.x];
    __syncthreads();

    int i = blockIdx.x * 256 + threadIdx.x;
    if (i >= n) return;
    float l0 = 0.f, l1 = 0.f;
#pragma unroll
    for (int sl = 0; sl < 8; ++sl) {
        const bf16x8* p = reinterpret_cast<const bf16x8*>(h + ((size_t)(sl * n + i)) * 16);
        bf16x8 qa = p[0], qb = p[1];
#pragma unroll
        for (int t = 0; t < 8; ++t) {
            float va = bf2f((unsigned short)qa[t]);
            float vb = bf2f((unsigned short)qb[t]);
            l0 += va * wc0[sl * 16 + t] + vb * wc0[sl * 16 + 8 + t];
            l1 += va * wc1[sl * 16 + t] + vb * wc1[sl * 16 + 8 + t];
        }
    }
    l0 += bcs[0]; l1 += bcs[1];
    float m = fmaxf(l0, l1);
    float lse = m + logf(expf(l0 - m) + expf(l1 - m));
    out[i * 2 + 0] = l0 - lse;
    out[i * 2 + 1] = l1 - lse;
}

// ---------------- launch ----------------

static inline size_t align256(size_t x) { return (x + 255) & ~(size_t)255; }

extern "C" void kernel_launch(void* const* d_in, const int* in_sizes, int n_in,
                              void* d_out, int out_size, void* d_ws, size_t ws_size,
                              hipStream_t stream) {
    const float* x   = (const float*)d_in[0];
    const int*   ei  = (const int*)d_in[1];     // int32 per harness contract
    const float* W1  = (const float*)d_in[2];
    const float* b1  = (const float*)d_in[3];
    const float* W2  = (const float*)d_in[4];
    const float* b2  = (const float*)d_in[5];
    const float* W3  = (const float*)d_in[6];
    const float* b3  = (const float*)d_in[7];
    const float* Wc  = (const float*)d_in[8];
    const float* bc  = (const float*)d_in[9];
    float*       out = (float*)d_out;

    const int* src = ei;             // edge_index[0,:]
    const int* dst = ei + N_EDGES;   // edge_index[1,:]

    // workspace layout
    size_t off = 0;
    size_t o_dinv    = off; off = align256(off + (size_t)N_NODES * 4);
    size_t o_rowptr  = off; off = align256(off + (size_t)(N_NODES + 1) * 4);
    size_t o_ccnt    = off; off = align256(off + (size_t)NB * N_CHUNKS * 4);
    size_t o_btot    = off; off = align256(off + (size_t)NB * 4);
    size_t o_bbase   = off; off = align256(off + (size_t)(NB + 1) * 4);
    size_t o_qc      = off; off = align256(off + (size_t)3 * 8 * QSTRIDE * 4);
    size_t o_csr     = off; off = align256(off + (size_t)N_EDGES * 4);
    size_t o_stg     = off; off = align256(off + (size_t)N_EDGES * 4);
    size_t o_blob1   = off; off = align256(off + (size_t)(F_IN / 32) * 8 * 64 * 8 * 2);
    size_t o_blob2   = off; off = align256(off + (size_t)(HID / 32) * 8 * 64 * 8 * 2);
    size_t o_blob3   = off; off = align256(off + (size_t)(HID / 32) * 8 * 64 * 8 * 2);
    size_t o_bufA    = off; off = align256(off + (size_t)N_NODES * HID * 2);
    size_t o_bufB    = off; off = align256(off + (size_t)N_NODES * HID * 2);
    size_t need = off;

    const int nThr = 256;
    const int gOut = (out_size + nThr - 1) / nThr;
    if (ws_size < need) {
        zero_f_kernel<<<gOut, nThr, 0, stream>>>(out, out_size);
        return;
    }

    char* ws = (char*)d_ws;
    float*          dinv    = (float*)(ws + o_dinv);
    int*            row_ptr = (int*)(ws + o_rowptr);
    int*            ccnt    = (int*)(ws + o_ccnt);
    int*            btot    = (int*)(ws + o_btot);
    int*            bbase   = (int*)(ws + o_bbase);
    int*            qcAll   = (int*)(ws + o_qc);
    int*            csr_src = (int*)(ws + o_csr);
    unsigned int*   stg     = (unsigned int*)(ws + o_stg);
    unsigned short* blob1   = (unsigned short*)(ws + o_blob1);
    unsigned short* blob2   = (unsigned short*)(ws + o_blob2);
    unsigned short* blob3   = (unsigned short*)(ws + o_blob3);
    unsigned short* bufA    = (unsigned short*)(ws + o_bufA);   // xw (sliced bf16)
    unsigned short* bufB    = (unsigned short*)(ws + o_bufB);   // h  (sliced bf16)

    const int gN = (N_NODES + nThr - 1) / nThr;
    const int gG = (N_NODES + 127) / 128;

    // ---- CSR build ----
    count_kernel<<<N_CHUNKS, nThr, 0, stream>>>(dst, ccnt, N_EDGES);
    scanA_kernel<<<NB, nThr, 0, stream>>>(ccnt, btot);
    scanB_kernel<<<1, 512, 0, stream>>>(btot, bbase, qcAll);
    stage_kernel<<<N_CHUNKS, nThr, 0, stream>>>(src, dst, ccnt, bbase, stg, N_EDGES);
    bucket_finalize_kernel<<<NB, nThr, 0, stream>>>(stg, bbase, dinv, row_ptr, csr_src, N_NODES);

    // ---- W blobs ----
    prep_blob_all_kernel<<<32, nThr, 0, stream>>>(W1, W2, W3, blob1, blob2, blob3);

    // ---- layers ----
    mfma_gemm_kernel<F_IN, false><<<gG, nThr, 0, stream>>>(x, blob1, bufA, N_NODES);
    agg_gather_aff_kernel<<<GATHER_BLOCKS, nThr, 0, stream>>>(bufA, dinv, row_ptr, csr_src,
                                                              b1, bufB, qcAll, N_NODES);

    mfma_gemm_kernel<HID, true><<<gG, nThr, 0, stream>>>(bufB, blob2, bufA, N_NODES);
    agg_gather_aff_kernel<<<GATHER_BLOCKS, nThr, 0, stream>>>(bufA, dinv, row_ptr, csr_src,
                                                              b2, bufB, qcAll + 8 * QSTRIDE, N_NODES);

    mfma_gemm_kernel<HID, true><<<gG, nThr, 0, stream>>>(bufB, blob3, bufA, N_NODES);
    agg_gather_aff_kernel<<<GATHER_BLOCKS, nThr, 0, stream>>>(bufA, dinv, row_ptr, csr_src,
                                                              b3, bufB, qcAll + 16 * QSTRIDE, N_NODES);

    // ---- classifier ----
    classifier_kernel<<<gN, nThr, 0, stream>>>(bufB, Wc, bc, out, N_NODES);
}

// Round 11
// 306.346 us; speedup vs baseline: 2.2005x; 2.2005x over previous
//
#include <hip/hip_runtime.h>
#include <hip/hip_bf16.h>
#include <cstdint>
#include <cstddef>

#define N_NODES 100000
#define N_EDGES 1600000
#define F_IN    256
#define HID     128
#define NB       ((N_NODES + 255) >> 8)                        // 391 dst-buckets
#define F3_CHUNK 7168
#define N_CHUNKS ((N_EDGES + F3_CHUNK - 1) / F3_CHUNK)         // 224

typedef __attribute__((ext_vector_type(8))) short  bf16x8;
typedef __attribute__((ext_vector_type(4))) float  f32x4;

static __device__ inline float bf2f(unsigned short u) {
    return __uint_as_float(((unsigned int)u) << 16);
}
static __device__ inline unsigned short f2bf(float f) {
    union { __hip_bfloat16 h; unsigned short u; } c;
    c.h = __float2bfloat16(f);
    return c.u;
}
static __device__ inline float lof(unsigned int w) { return __uint_as_float(w << 16); }
static __device__ inline float hif(unsigned int w) { return __uint_as_float(w & 0xffff0000u); }

// ---------------- utility ----------------

__global__ __launch_bounds__(256) void zero_f_kernel(float* __restrict__ p, int n) {
    int i = blockIdx.x * 256 + threadIdx.x;
    if (i < n) p[i] = 0.f;
}

// ---------------- W -> fragment blob helper ----------------

static __device__ inline void blob_fill(const float* __restrict__ W,
                                        unsigned short* __restrict__ blob, int tid) {
    int lane = tid & 63;
    int c    = (tid >> 6) & 7;
    int s    = tid >> 9;
    int col  = c * 16 + (lane & 15);
    int kb   = s * 32 + (lane >> 4) * 8;
    bf16x8 o;
#pragma unroll
    for (int j = 0; j < 8; ++j)
        o[j] = (short)f2bf(W[(size_t)(kb + j) * HID + col]);
    *reinterpret_cast<bf16x8*>(blob + (size_t)tid * 8) = o;
}

// ---------------- fused count + blob prep ----------------
// blocks 0..N_CHUNKS-1: per-chunk dst-bucket histogram -> ccnt[b][chunk]
// blocks N_CHUNKS..N_CHUNKS+31: W blobs (independent work, merged launch)

__global__ __launch_bounds__(256) void count_blob_kernel(const int* __restrict__ dst,
                                                         int* __restrict__ ccnt, int nE,
                                                         const float* __restrict__ W1,
                                                         const float* __restrict__ W2,
                                                         const float* __restrict__ W3,
                                                         unsigned short* __restrict__ blob1,
                                                         unsigned short* __restrict__ blob2,
                                                         unsigned short* __restrict__ blob3) {
    if (blockIdx.x >= N_CHUNKS) {
        int blk = blockIdx.x - N_CHUNKS;
        if (blk < 16)      blob_fill(W1, blob1, blk * 256 + threadIdx.x);
        else if (blk < 24) blob_fill(W2, blob2, (blk - 16) * 256 + threadIdx.x);
        else               blob_fill(W3, blob3, (blk - 24) * 256 + threadIdx.x);
        return;
    }
    __shared__ int c[NB];
    for (int i = threadIdx.x; i < NB; i += 256) c[i] = 0;
    __syncthreads();
    int base = blockIdx.x * F3_CHUNK;
    int m = min(F3_CHUNK, nE - base);
    for (int t = threadIdx.x; t < m; t += 256)
        atomicAdd(&c[dst[base + t] >> 8], 1);
    __syncthreads();
    for (int i = threadIdx.x; i < NB; i += 256)
        ccnt[i * N_CHUNKS + blockIdx.x] = c[i];
}

// scanA: per-bucket exclusive scan over its 224 chunk counts (in place) + total

__global__ __launch_bounds__(256) void scanA_kernel(int* __restrict__ ccnt,
                                                    int* __restrict__ btot) {
    __shared__ int s[256];
    const int b = blockIdx.x;
    const int t = threadIdx.x;
    int v = (t < N_CHUNKS) ? ccnt[b * N_CHUNKS + t] : 0;
    s[t] = v;
    __syncthreads();
    for (int off = 1; off < 256; off <<= 1) {
        int add = (t >= off) ? s[t - off] : 0;
        __syncthreads();
        s[t] += add;
        __syncthreads();
    }
    if (t < N_CHUNKS) ccnt[b * N_CHUNKS + t] = s[t] - v;   // exclusive
    if (t == 255) btot[b] = s[255];                        // bucket total
}

// scanB: exclusive scan of 391 bucket totals -> bbase

__global__ __launch_bounds__(512) void scanB_kernel(const int* __restrict__ btot,
                                                    int* __restrict__ bbase) {
    __shared__ int s[512];
    int t = threadIdx.x;
    int v = (t < NB) ? btot[t] : 0;
    s[t] = v;
    __syncthreads();
    for (int off = 1; off < 512; off <<= 1) {
        int add = (t >= off) ? s[t - off] : 0;
        __syncthreads();
        s[t] += add;
        __syncthreads();
    }
    if (t < NB) bbase[t] = s[t] - v;
    if (t == 0) bbase[NB] = N_EDGES;
}

// stage (single pass): slot = bbase[b] + ccnt[b][chunk] + LDS-cnt++
// writes packed (src<<8)|(dst&255) grouped by dst-bucket

__global__ __launch_bounds__(256) void stage_kernel(const int* __restrict__ src,
                                                    const int* __restrict__ dst,
                                                    const int* __restrict__ ccnt,
                                                    const int* __restrict__ bbase,
                                                    unsigned int* __restrict__ stg, int nE) {
    __shared__ int cnt[NB];
    __shared__ int bas[NB];
    const int chunk = blockIdx.x;
    for (int i = threadIdx.x; i < NB; i += 256) {
        cnt[i] = 0;
        bas[i] = bbase[i] + ccnt[i * N_CHUNKS + chunk];
    }
    __syncthreads();
    int base = chunk * F3_CHUNK;
    int m = min(F3_CHUNK, nE - base);
    for (int t = threadIdx.x; t < m; t += 256) {
        int d = dst[base + t];
        int s = src[base + t];
        int bkt = d >> 8;
        int k = atomicAdd(&cnt[bkt], 1);
        stg[bas[bkt] + k] = ((unsigned int)s << 8) | (unsigned int)(d & 255);
    }
}

// fused finalize: per-bucket deg -> dinv, LDS scan -> row_ptr, fill -> csr_src

__global__ __launch_bounds__(256) void bucket_finalize_kernel(
        const unsigned int* __restrict__ stg,
        const int* __restrict__ bbase,
        float* __restrict__ dinv,
        int* __restrict__ row_ptr,
        int* __restrict__ csr_src, int n) {
    __shared__ int c[256];
    __shared__ int s[256];
    __shared__ int lofs[256];
    const int b = blockIdx.x;
    const int t = threadIdx.x;
    const int beg = bbase[b], end = bbase[b + 1];

    c[t] = 0;
    __syncthreads();
    for (int i = beg + t; i < end; i += 256)
        atomicAdd(&c[stg[i] & 255u], 1);
    __syncthreads();

    const int node = b * 256 + t;
    const int myDeg = c[t];
    if (node < n) dinv[node] = rsqrtf((float)myDeg + 1.0f);   // +1 self-loop

    s[t] = myDeg;
    __syncthreads();
    for (int off = 1; off < 256; off <<= 1) {
        int add = (t >= off) ? s[t - off] : 0;
        __syncthreads();
        s[t] += add;
        __syncthreads();
    }
    const int excl = s[t] - myDeg;
    lofs[t] = excl;
    if (node <= n) row_ptr[node] = beg + excl;

    __syncthreads();
    c[t] = 0;
    __syncthreads();
    for (int i = beg + t; i < end; i += 256) {
        unsigned int p = stg[i];
        int dl = (int)(p & 255u);
        int k = atomicAdd(&c[dl], 1);
        csr_src[beg + lofs[dl] + k] = (int)(p >> 8);
    }
}

// ---------------- MFMA GEMM: Y_bf16[N,128] = X[N,K] @ W[K,128] --------------

template <int K, bool IN_BF16>
__global__ __launch_bounds__(256) void mfma_gemm_kernel(const void* __restrict__ Xv,
                                                        const unsigned short* __restrict__ blob,
                                                        unsigned short* __restrict__ Y, int n) {
    constexpr int KSTEPS = K / 32;
    const int lane = threadIdx.x & 63;
    const int wave = threadIdx.x >> 6;
    const int rowbase = blockIdx.x * 128 + wave * 32;

    const int r0 = min(rowbase +      (lane & 15), n - 1);
    const int r1 = min(rowbase + 16 + (lane & 15), n - 1);
    const int koff = (lane >> 4) * 8;

    f32x4 acc0[8], acc1[8];
#pragma unroll
    for (int c = 0; c < 8; ++c) { acc0[c] = (f32x4)0.f; acc1[c] = (f32x4)0.f; }

#pragma unroll
    for (int s = 0; s < KSTEPS; ++s) {
        bf16x8 bfr[8];
#pragma unroll
        for (int c = 0; c < 8; ++c)
            bfr[c] = *reinterpret_cast<const bf16x8*>(blob + ((size_t)((s * 8 + c) * 64 + lane)) * 8);

        bf16x8 a0, a1;
        if (IN_BF16) {
            const unsigned short* Xb = (const unsigned short*)Xv;
            a0 = *reinterpret_cast<const bf16x8*>(Xb + (size_t)r0 * K + s * 32 + koff);
            a1 = *reinterpret_cast<const bf16x8*>(Xb + (size_t)r1 * K + s * 32 + koff);
        } else {
            const float* Xf = (const float*)Xv;
            const float4* p0 = reinterpret_cast<const float4*>(Xf + (size_t)r0 * K + s * 32 + koff);
            const float4* p1 = reinterpret_cast<const float4*>(Xf + (size_t)r1 * K + s * 32 + koff);
            float4 q0 = p0[0], q1 = p0[1], q2 = p1[0], q3 = p1[1];
            a0[0] = (short)f2bf(q0.x); a0[1] = (short)f2bf(q0.y);
            a0[2] = (short)f2bf(q0.z); a0[3] = (short)f2bf(q0.w);
            a0[4] = (short)f2bf(q1.x); a0[5] = (short)f2bf(q1.y);
            a0[6] = (short)f2bf(q1.z); a0[7] = (short)f2bf(q1.w);
            a1[0] = (short)f2bf(q2.x); a1[1] = (short)f2bf(q2.y);
            a1[2] = (short)f2bf(q2.z); a1[3] = (short)f2bf(q2.w);
            a1[4] = (short)f2bf(q3.x); a1[5] = (short)f2bf(q3.y);
            a1[6] = (short)f2bf(q3.z); a1[7] = (short)f2bf(q3.w);
        }

#pragma unroll
        for (int c = 0; c < 8; ++c) {
            acc0[c] = __builtin_amdgcn_mfma_f32_16x16x32_bf16(a0, bfr[c], acc0[c], 0, 0, 0);
            acc1[c] = __builtin_amdgcn_mfma_f32_16x16x32_bf16(a1, bfr[c], acc1[c], 0, 0, 0);
        }
    }

    const int col  = lane & 15;
    const int rsub = (lane >> 4) * 4;
#pragma unroll
    for (int c = 0; c < 8; ++c) {
#pragma unroll
        for (int r = 0; r < 4; ++r) {
            int row0 = rowbase + rsub + r;
            int row1 = rowbase + 16 + rsub + r;
            if (row0 < n) Y[(size_t)row0 * HID + c * 16 + col] = f2bf(acc0[c][r]);
            if (row1 < n) Y[(size_t)row1 * HID + c * 16 + col] = f2bf(acc1[c][r]);
        }
    }
}

// ---------------- aggregation (gather, one wave per node, scalarized) -------
// h[v] = relu( dinv[v]*sum_s dinv[s]*xw[s] + dinv[v]^2*xw[v] + b )
// Wave-scalar edge loop (readfirstlane -> s_loads), 8-edge unroll for deeper
// prefetch window. CLS fuses classifier + log_softmax on the last layer.

template <bool CLS>
__global__ __launch_bounds__(256) void agg_gather_kernel(const unsigned short* __restrict__ xw,
                                                         const float* __restrict__ dinv,
                                                         const int* __restrict__ row_ptr,
                                                         const int* __restrict__ csr_src,
                                                         const float* __restrict__ b,
                                                         unsigned short* __restrict__ h,
                                                         const float* __restrict__ Wc,
                                                         const float* __restrict__ bc,
                                                         float* __restrict__ out, int n) {
    int v = (blockIdx.x * 256 + threadIdx.x) >> 6;
    if (v >= n) return;
    int lane = threadIdx.x & 63;

    int beg = __builtin_amdgcn_readfirstlane(row_ptr[v]);
    int end = __builtin_amdgcn_readfirstlane(row_ptr[v + 1]);

    const unsigned int* xw32 = (const unsigned int*)xw;   // 2 bf16 per word
    float a0 = 0.f, a1 = 0.f;                              // cols 2*lane, 2*lane+1

    int j = beg;
    for (; j + 8 <= end; j += 8) {
        int sx[8];
#pragma unroll
        for (int k = 0; k < 8; ++k)
            sx[k] = __builtin_amdgcn_readfirstlane(csr_src[j + k]);
        float dx[8];
#pragma unroll
        for (int k = 0; k < 8; ++k) dx[k] = dinv[sx[k]];
        unsigned int wx[8];
#pragma unroll
        for (int k = 0; k < 8; ++k) wx[k] = xw32[(size_t)sx[k] * 64 + lane];
#pragma unroll
        for (int k = 0; k < 8; ++k) {
            a0 = fmaf(dx[k], lof(wx[k]), a0);
            a1 = fmaf(dx[k], hif(wx[k]), a1);
        }
    }
    for (; j + 2 <= end; j += 2) {
        int s0 = __builtin_amdgcn_readfirstlane(csr_src[j]);
        int s1 = __builtin_amdgcn_readfirstlane(csr_src[j + 1]);
        float d0 = dinv[s0], d1 = dinv[s1];
        unsigned int w0 = xw32[(size_t)s0 * 64 + lane];
        unsigned int w1 = xw32[(size_t)s1 * 64 + lane];
        a0 = fmaf(d0, lof(w0), a0); a1 = fmaf(d0, hif(w0), a1);
        a0 = fmaf(d1, lof(w1), a0); a1 = fmaf(d1, hif(w1), a1);
    }
    if (j < end) {
        int s0 = __builtin_amdgcn_readfirstlane(csr_src[j]);
        float d0 = dinv[s0];
        unsigned int w0 = xw32[(size_t)s0 * 64 + lane];
        a0 = fmaf(d0, lof(w0), a0); a1 = fmaf(d0, hif(w0), a1);
    }

    float dv = dinv[v];
    unsigned int wv = xw32[(size_t)v * 64 + lane];
    float2 bb = *reinterpret_cast<const float2*>(b + 2 * lane);
    float s2v = dv * dv;
    float r0 = fmaxf(dv * a0 + s2v * lof(wv) + bb.x, 0.f);
    float r1 = fmaxf(dv * a1 + s2v * hif(wv) + bb.y, 0.f);

    if (!CLS) {
        unsigned int o = (unsigned int)f2bf(r0) | ((unsigned int)f2bf(r1) << 16);
        *reinterpret_cast<unsigned int*>(h + (size_t)v * HID + 2 * lane) = o;
    } else {
        float4 qw = *reinterpret_cast<const float4*>(Wc + 4 * lane);
        float p0 = r0 * qw.x + r1 * qw.z;
        float p1 = r0 * qw.y + r1 * qw.w;
#pragma unroll
        for (int off = 1; off < 64; off <<= 1) {
            p0 += __shfl_xor(p0, off);
            p1 += __shfl_xor(p1, off);
        }
        if (lane == 0) {
            float l0 = p0 + bc[0];
            float l1 = p1 + bc[1];
            float m = fmaxf(l0, l1);
            float lse = m + logf(expf(l0 - m) + expf(l1 - m));
            out[(size_t)v * 2 + 0] = l0 - lse;
            out[(size_t)v * 2 + 1] = l1 - lse;
        }
    }
}

// ---------------- launch ----------------

static inline size_t align256(size_t x) { return (x + 255) & ~(size_t)255; }

extern "C" void kernel_launch(void* const* d_in, const int* in_sizes, int n_in,
                              void* d_out, int out_size, void* d_ws, size_t ws_size,
                              hipStream_t stream) {
    const float* x   = (const float*)d_in[0];
    const int*   ei  = (const int*)d_in[1];     // int32 per harness contract
    const float* W1  = (const float*)d_in[2];
    const float* b1  = (const float*)d_in[3];
    const float* W2  = (const float*)d_in[4];
    const float* b2  = (const float*)d_in[5];
    const float* W3  = (const float*)d_in[6];
    const float* b3  = (const float*)d_in[7];
    const float* Wc  = (const float*)d_in[8];
    const float* bc  = (const float*)d_in[9];
    float*       out = (float*)d_out;

    const int* src = ei;             // edge_index[0,:]
    const int* dst = ei + N_EDGES;   // edge_index[1,:]

    // workspace layout
    size_t off = 0;
    size_t o_dinv    = off; off = align256(off + (size_t)N_NODES * 4);
    size_t o_rowptr  = off; off = align256(off + (size_t)(N_NODES + 1) * 4);
    size_t o_ccnt    = off; off = align256(off + (size_t)NB * N_CHUNKS * 4);
    size_t o_btot    = off; off = align256(off + (size_t)NB * 4);
    size_t o_bbase   = off; off = align256(off + (size_t)(NB + 1) * 4);
    size_t o_csr     = off; off = align256(off + (size_t)N_EDGES * 4);
    size_t o_stg     = off; off = align256(off + (size_t)N_EDGES * 4);
    size_t o_blob1   = off; off = align256(off + (size_t)(F_IN / 32) * 8 * 64 * 8 * 2);
    size_t o_blob2   = off; off = align256(off + (size_t)(HID / 32) * 8 * 64 * 8 * 2);
    size_t o_blob3   = off; off = align256(off + (size_t)(HID / 32) * 8 * 64 * 8 * 2);
    size_t o_bufA    = off; off = align256(off + (size_t)N_NODES * HID * 2);
    size_t o_bufB    = off; off = align256(off + (size_t)N_NODES * HID * 2);
    size_t need = off;                           // ~65.5 MB

    const int nThr = 256;
    const int gOut = (out_size + nThr - 1) / nThr;
    if (ws_size < need) {
        zero_f_kernel<<<gOut, nThr, 0, stream>>>(out, out_size);
        return;
    }

    char* ws = (char*)d_ws;
    float*          dinv    = (float*)(ws + o_dinv);
    int*            row_ptr = (int*)(ws + o_rowptr);
    int*            ccnt    = (int*)(ws + o_ccnt);
    int*            btot    = (int*)(ws + o_btot);
    int*            bbase   = (int*)(ws + o_bbase);
    int*            csr_src = (int*)(ws + o_csr);
    unsigned int*   stg     = (unsigned int*)(ws + o_stg);
    unsigned short* blob1   = (unsigned short*)(ws + o_blob1);
    unsigned short* blob2   = (unsigned short*)(ws + o_blob2);
    unsigned short* blob3   = (unsigned short*)(ws + o_blob3);
    unsigned short* bufA    = (unsigned short*)(ws + o_bufA);   // xw (bf16)
    unsigned short* bufB    = (unsigned short*)(ws + o_bufB);   // h  (bf16)

    const int gW = (N_NODES * 64 + nThr - 1) / nThr;   // one wave per node
    const int gG = (N_NODES + 127) / 128;

    // ---- CSR build + blob prep (4 launches) ----
    count_blob_kernel<<<N_CHUNKS + 32, nThr, 0, stream>>>(dst, ccnt, N_EDGES,
                                                          W1, W2, W3, blob1, blob2, blob3);
    scanA_kernel<<<NB, nThr, 0, stream>>>(ccnt, btot);
    scanB_kernel<<<1, 512, 0, stream>>>(btot, bbase);
    stage_kernel<<<N_CHUNKS, nThr, 0, stream>>>(src, dst, ccnt, bbase, stg, N_EDGES);
    bucket_finalize_kernel<<<NB, nThr, 0, stream>>>(stg, bbase, dinv, row_ptr, csr_src, N_NODES);

    // ---- layers ----
    mfma_gemm_kernel<F_IN, false><<<gG, nThr, 0, stream>>>(x, blob1, bufA, N_NODES);
    agg_gather_kernel<false><<<gW, nThr, 0, stream>>>(bufA, dinv, row_ptr, csr_src, b1,
                                                      bufB, nullptr, nullptr, nullptr, N_NODES);

    mfma_gemm_kernel<HID, true><<<gG, nThr, 0, stream>>>(bufB, blob2, bufA, N_NODES);
    agg_gather_kernel<false><<<gW, nThr, 0, stream>>>(bufA, dinv, row_ptr, csr_src, b2,
                                                      bufB, nullptr, nullptr, nullptr, N_NODES);

    mfma_gemm_kernel<HID, true><<<gG, nThr, 0, stream>>>(bufB, blob3, bufA, N_NODES);
    agg_gather_kernel<true><<<gW, nThr, 0, stream>>>(bufA, dinv, row_ptr, csr_src, b3,
                                                     nullptr, Wc, bc, out, N_NODES);
}